// Round 6
// baseline (272.965 us; speedup 1.0000x reference)
//
#include <hip/hip_runtime.h>

#define NB 32768

typedef _Float16 half8 __attribute__((ext_vector_type(8)));
typedef float floatx4 __attribute__((ext_vector_type(4)));
typedef unsigned int uint4v __attribute__((ext_vector_type(4)));

#define MFMA16(a,b,c) __builtin_amdgcn_mfma_f32_16x16x32_f16(a,b,c,0,0,0)

// ---------- fast math ----------
__device__ __forceinline__ float rcp_f(float x){ return __builtin_amdgcn_rcpf(x); }
__device__ __forceinline__ float exp2_f(float x){ return __builtin_amdgcn_exp2f(x); }
__device__ __forceinline__ float tanh_f(float x){
  float e = exp2_f(x * 2.8853900817779268f);     // e^(2x)
  return (e - 1.0f) * rcp_f(e + 1.0f);
}
__device__ __forceinline__ float sigmoid_f(float x){
  return rcp_f(1.0f + exp2_f(-1.4426950408889634f * x));
}

// DPP quad butterflies: xor1 = quad_perm[1,0,3,2]=0xB1, xor2 = [2,3,0,1]=0x4E
template<int CTRL>
__device__ __forceinline__ float dpp_qp(float x){
  return __builtin_bit_cast(float, __builtin_amdgcn_update_dpp(0, __builtin_bit_cast(int,x), CTRL, 0xF, 0xF, true));
}
__device__ __forceinline__ float qadd2(float x){
  x += dpp_qp<0xB1>(x);
  x += dpp_qp<0x4E>(x);
  return x;
}
__device__ __forceinline__ float qmax2(float x){
  x = fmaxf(x, dpp_qp<0xB1>(x));
  x = fmaxf(x, dpp_qp<0x4E>(x));
  return x;
}

// ---------- f16 weight region offsets (in _Float16 units), lives in d_ws ----------
constexpr int O_AW0H = 0;        // 256x128
constexpr int O_AW1H = 32768;    // 128x128
constexpr int O_AW2H = 49152;
constexpr int O_AW3H = 65536;    // 128x256
constexpr int O_PW0H = 98304;
constexpr int O_PW1H = 131072;
constexpr int O_PW2H = 147456;
constexpr int O_PW3H = 163840;   // 128x16
constexpr int O_AW1L = 165888;
constexpr int O_AW2L = 182272;
constexpr int O_AW3L = 198656;

// ---------- weight prep: transpose + split f32 -> f16 hi/lo ----------
struct PrepJob { const float* src; _Float16* h; _Float16* l; int kshift; int total; };
struct PrepJobs { PrepJob j[8]; };

__global__ void prep_kernel(PrepJobs js){
  const PrepJob jb = js.j[blockIdx.y];
  const int idx = blockIdx.x*256 + threadIdx.x;
  if (idx >= jb.total) return;
  const int K = 1 << jb.kshift;
  const int n = idx >> jb.kshift;
  const int k = idx & (K-1);
  const int N = jb.total >> jb.kshift;
  float w = jb.src[(long)k*N + n];
  _Float16 h = (_Float16)w;
  jb.h[idx] = h;
  if (jb.l) jb.l[idx] = (_Float16)(w - (float)h);
}

// ---------- a-net LDS act: 16 rows x 128 cols packed (hi|lo) u32, 16B-chunk XOR swizzle ----------
__device__ __forceinline__ int aaddr(int row, int col){
  int cc = (col >> 2) ^ (row & 7);
  return row*128 + (cc<<2) + (col & 3);
}

template<bool NEED_LO>
__device__ __forceinline__ void read_frag(const unsigned int* __restrict__ act,
    int row, int ks, int q, half8& ah, half8& al)
{
  const int s = row & 7;
  const int cc0 = ks*8 + q*2;
  uint4v c0 = *(const uint4v*)(act + row*128 + (((cc0  ) ^ s)<<2));
  uint4v c1 = *(const uint4v*)(act + row*128 + (((cc0+1) ^ s)<<2));
  uint4v h;
  h.x = (c0.x & 0xffffu) | (c0.y << 16);
  h.y = (c0.z & 0xffffu) | (c0.w << 16);
  h.z = (c1.x & 0xffffu) | (c1.y << 16);
  h.w = (c1.z & 0xffffu) | (c1.w << 16);
  ah = __builtin_bit_cast(half8, h);
  if constexpr (NEED_LO){
    uint4v g;
    g.x = (c0.x >> 16) | (c0.y & 0xffff0000u);
    g.y = (c0.z >> 16) | (c0.w & 0xffff0000u);
    g.z = (c1.x >> 16) | (c1.y & 0xffff0000u);
    g.w = (c1.z >> 16) | (c1.w & 0xffff0000u);
    al = __builtin_bit_cast(half8, g);
  }
}

__device__ __forceinline__ unsigned int pack_act(float v){
  _Float16 h = (_Float16)v;
  _Float16 lo = (_Float16)(v - (float)h);
  return (unsigned int)__builtin_bit_cast(unsigned short, h)
       | ((unsigned int)__builtin_bit_cast(unsigned short, lo) << 16);
}

// ---------- p-net LDS act: 16 rows x 128 cols f16 (u16), 16B-chunk (8 cols) XOR swizzle ----------
__device__ __forceinline__ half8 read_frag_h(const unsigned short* __restrict__ act,
    int row, int ks, int q)
{
  const int c8 = (ks*4 + q) ^ (row & 15);
  return *(const half8*)(act + row*128 + (c8<<3));
}

__device__ __forceinline__ half8 load_xfrag(const float* __restrict__ X, long row, int k0){
  float4 a = *(const float4*)(X + row*256 + k0);
  float4 b = *(const float4*)(X + row*256 + k0 + 4);
  half8 h;
  h[0]=(_Float16)a.x; h[1]=(_Float16)a.y; h[2]=(_Float16)a.z; h[3]=(_Float16)a.w;
  h[4]=(_Float16)b.x; h[5]=(_Float16)b.y; h[6]=(_Float16)b.z; h[7]=(_Float16)b.w;
  return h;
}

// ---------- MFMA inner block: 1 m-tile x NT n-tiles, K = KS*32 ----------
template<int KS, int PASSES, int NT>
__device__ __forceinline__ void mfma_block(
    const half8* Ah, const half8* Al,
    const _Float16* __restrict__ Wh, const _Float16* __restrict__ Wl,
    int K, int l15, int q, floatx4* acc)
{
#pragma unroll
  for (int nt=0; nt<NT; ++nt){
    const _Float16* bp = Wh + (nt*16 + l15)*K + q*8;
#pragma unroll
    for (int ks=0; ks<KS; ++ks){
      half8 bh = *(const half8*)(bp + ks*32);
      acc[nt] = MFMA16(Ah[ks], bh, acc[nt]);
      if constexpr (PASSES == 3){
        const _Float16* blp = Wl + (nt*16 + l15)*K + q*8;
        half8 bl = *(const half8*)(blp + ks*32);
        acc[nt] = MFMA16(Al[ks], bh, acc[nt]);
        acc[nt] = MFMA16(Ah[ks], bl, acc[nt]);
      }
    }
  }
}

// a-net epilogue: bias+tanh+pack (hi|lo) to act_a
__device__ __forceinline__ void epi_tanh(floatx4* acc, const float* __restrict__ bias,
    unsigned int* __restrict__ act, int q, int l15)
{
#pragma unroll
  for (int nt=0; nt<8; ++nt){
    float bb = bias[nt*16 + l15];
#pragma unroll
    for (int r=0; r<4; ++r){
      float t = tanh_f(acc[nt][r] + bb);
      act[aaddr(q*4 + r, nt*16 + l15)] = pack_act(t);
    }
  }
}

// p-net epilogue: bias+tanh, f16 u16 store
__device__ __forceinline__ void epi_tanh_h(floatx4* acc, const float* __restrict__ bias,
    unsigned short* __restrict__ act, int q, int l15)
{
#pragma unroll
  for (int nt=0; nt<8; ++nt){
    float bb = bias[nt*16 + l15];
#pragma unroll
    for (int r=0; r<4; ++r){
      float t = tanh_f(acc[nt][r] + bb);
      const int row = q*4 + r, col = nt*16 + l15;
      const int c8 = (col >> 3) ^ (row & 15);
      act[row*128 + (c8<<3) + (col&7)] = __builtin_bit_cast(unsigned short, (_Float16)t);
    }
  }
}

template<int PASSES>
__device__ __forceinline__ void hidden128(unsigned int* __restrict__ act,
    const _Float16* __restrict__ Wh, const _Float16* __restrict__ Wl,
    const float* __restrict__ bias, int q, int l15)
{
  half8 Ah[4], Al[4];
#pragma unroll
  for (int ks=0; ks<4; ++ks)
    read_frag<PASSES==3>(act, l15, ks, q, Ah[ks], Al[ks]);
  floatx4 acc[8];
#pragma unroll
  for (int nt=0; nt<8; ++nt) acc[nt] = (floatx4)0.0f;
  mfma_block<4,PASSES,8>(Ah, Al, Wh, Wl, 128, l15, q, acc);
  epi_tanh(acc, bias, act, q, l15);
}

__device__ __forceinline__ void hidden128_h(unsigned short* __restrict__ act,
    const _Float16* __restrict__ Wh, const float* __restrict__ bias, int q, int l15)
{
  half8 Ah[4];
#pragma unroll
  for (int ks=0; ks<4; ++ks)
    Ah[ks] = read_frag_h(act, l15, ks, q);
  floatx4 acc[8];
#pragma unroll
  for (int nt=0; nt<8; ++nt) acc[nt] = (floatx4)0.0f;
  mfma_block<4,1,8>(Ah, Ah, Wh, Wh, 128, l15, q, acc);
  epi_tanh_h(acc, bias, act, q, l15);
}

// ================= Fused kernel: MLPs + Sinkhorn + payments =================
// 64 threads = 1 wave per block, 16 rows/block, zero barriers (wave-local LDS, in-order).
// LDS (13312 B): [0..8192) act_a u32 hi|lo; [8192..12288) act_p u16;
//                [12288..13312) frac f32.
// aug overlay: 16 rows x 132 f32 (8448 B) over [0..8448) — act_a dead (pre-read to regs),
// act_p dead (pL4 precedes aL4). Two 128-col halves processed through the same buffer.
__global__ __launch_bounds__(64, 3) void fused_kernel(
  const float* __restrict__ X, const _Float16* __restrict__ WT,
  const float* __restrict__ ab0, const float* __restrict__ ab1,
  const float* __restrict__ ab2, const float* __restrict__ ab3,
  const float* __restrict__ pb0, const float* __restrict__ pb1,
  const float* __restrict__ pb2, const float* __restrict__ pb3,
  float* __restrict__ out)
{
  __shared__ unsigned int S[3328];   // 13312 B
  unsigned int* act_a = S;
  unsigned short* act_p = (unsigned short*)(S + 2048);
  float* frac_l = (float*)(S + 3072);
  const int l = threadIdx.x, q = l>>4, l15 = l&15;
  const long rb = (long)blockIdx.x * 16;

  // ---- L1 of both nets from one X fragment set (K=256) ----
  {
    half8 Xf[8];
#pragma unroll
    for (int ks=0; ks<8; ++ks)
      Xf[ks] = load_xfrag(X, rb + l15, ks*32 + q*8);
    floatx4 acca[8], accp[8];
#pragma unroll
    for (int nt=0; nt<8; ++nt){ acca[nt] = (floatx4)0.0f; accp[nt] = (floatx4)0.0f; }
    mfma_block<8,1,8>(Xf, Xf, WT+O_AW0H, WT+O_AW0H, 256, l15, q, acca);
    mfma_block<8,1,8>(Xf, Xf, WT+O_PW0H, WT+O_PW0H, 256, l15, q, accp);
    epi_tanh(acca, ab0, act_a, q, l15);
    epi_tanh_h(accp, pb0, act_p, q, l15);
  }
  // ---- hidden layers interleaved: a (3-pass split-corrected), p (1-pass f16) ----
  hidden128<3>(act_a, WT+O_AW1H, WT+O_AW1L, ab1, q, l15);
  hidden128_h(act_p, WT+O_PW1H, pb1, q, l15);
  hidden128<3>(act_a, WT+O_AW2H, WT+O_AW2L, ab2, q, l15);
  hidden128_h(act_p, WT+O_PW2H, pb2, q, l15);

  // ---- p-net L4 -> frac (sigmoid) to LDS — MUST precede aL4's aug overlay ----
  {
    half8 Ah[4];
#pragma unroll
    for (int ks=0; ks<4; ++ks)
      Ah[ks] = read_frag_h(act_p, l15, ks, q);
    floatx4 acc1 = (floatx4)0.0f;
    mfma_block<4,1,1>(Ah, Ah, WT+O_PW3H, WT+O_PW3H, 128, l15, q, &acc1);
    float bb = pb3[l15];
#pragma unroll
    for (int r=0; r<4; ++r)
      frac_l[(q*4+r)*16 + l15] = sigmoid_f(acc1[r] + bb);
  }

  // ---- a-net L4 (split-corrected) -> aug halves in LDS, Kx pulled per half ----
  const int c = l & 3;
  const int eL = l >> 2;                 // local element 0..15
  const float Ssc = 14.426950408889634f; // (1/EPS)/ln2 : logits in exp2 units
  float Kx[4][17];   // owned cols (4c+cc), rows 0..16 (row 16 = pad row)
  {
    half8 Ah[4], Al[4];
#pragma unroll
    for (int ks=0; ks<4; ++ks)
      read_frag<true>(act_a, l15, ks, q, Ah[ks], Al[ks]);
    float* augl = (float*)S;             // 16 x 132 f32 overlay
#pragma unroll
    for (int hf=0; hf<2; ++hf){
      floatx4 acc[8];
#pragma unroll
      for (int nt=0; nt<8; ++nt) acc[nt] = (floatx4)0.0f;
      mfma_block<4,3,8>(Ah, Al, WT+O_AW3H + hf*128*128, WT+O_AW3L + hf*128*128, 128, l15, q, acc);
      const int ncol0 = hf*128;
#pragma unroll
      for (int nt=0; nt<8; ++nt){
        float bb = ab3[ncol0 + nt*16 + l15];
#pragma unroll
        for (int r=0; r<4; ++r)
          augl[(q*4+r)*132 + nt*16 + l15] = acc[nt][r] + bb;
      }
      // pull my Kx rows a = hf*8 .. hf*8+7 (wave-local in-order LDS: no barrier)
#pragma unroll
      for (int al=0; al<8; ++al){
        float4 v = *(const float4*)(augl + eL*132 + al*16 + 4*c);
        Kx[0][hf*8+al]=v.x*Ssc; Kx[1][hf*8+al]=v.y*Ssc;
        Kx[2][hf*8+al]=v.z*Ssc; Kx[3][hf*8+al]=v.w*Ssc;
      }
    }
  }
  Kx[0][16]=0.f; Kx[1][16]=0.f; Kx[2][16]=0.f; Kx[3][16]=0.f;

  // ================= Sinkhorn + payments (wave-local) =================
  const long e = rb + eL;                // global element
  const float cmask = (c == 3) ? 1.0f : 0.0f;
  float K16[17];     // pad column 16 (lane 3 only; zeroed elsewhere)
  float u[17];
#pragma unroll
  for (int i=0;i<17;++i){
    float mm = fmaxf(fmaxf(Kx[0][i],Kx[1][i]), fmaxf(Kx[2][i],Kx[3][i]));
    mm = fmaxf(mm, 0.0f);
    mm = qmax2(mm);
    Kx[0][i] = exp2_f(Kx[0][i]-mm);
    Kx[1][i] = exp2_f(Kx[1][i]-mm);
    Kx[2][i] = exp2_f(Kx[2][i]-mm);
    Kx[3][i] = exp2_f(Kx[3][i]-mm);
    K16[i]   = cmask * exp2_f(-mm);
  }

  float vj0=1.f, vj1=1.f, vj2=1.f, vj3=1.f;
  float v16 = cmask;

  for (int r=0;r<40;++r){
#pragma unroll
    for (int i=0;i<17;++i){
      float p = Kx[0][i]*vj0 + Kx[1][i]*vj1 + Kx[2][i]*vj2 + Kx[3][i]*vj3 + K16[i]*v16;
      p = qadd2(p);
      u[i] = rcp_f(p);
    }
    u[16] *= 16.0f;   // a_16 = I = 16
    float t0=0.f,t1=0.f,t2=0.f,t3=0.f,t16=0.f;
#pragma unroll
    for (int i=0;i<17;++i){
      t0  = fmaf(Kx[0][i],u[i],t0);
      t1  = fmaf(Kx[1][i],u[i],t1);
      t2  = fmaf(Kx[2][i],u[i],t2);
      t3  = fmaf(Kx[3][i],u[i],t3);
      t16 = fmaf(K16[i], u[i],t16);
    }
    vj0 = rcp_f(t0); vj1 = rcp_f(t1); vj2 = rcp_f(t2); vj3 = rcp_f(t3);
    v16 = cmask * 16.0f * rcp_f(t16 + 1e-30f + (1.0f - cmask));  // b_16 = A = 16; NaN-guard off-lane
  }

  // allocs = u_i * K_ij * v_j  (real 16x16 block)
  float* op = out + e*256 + 4*c;
#pragma unroll
  for (int i=0;i<16;++i){
    float4 w;
    w.x = u[i]*Kx[0][i]*vj0;
    w.y = u[i]*Kx[1][i]*vj1;
    w.z = u[i]*Kx[2][i]*vj2;
    w.w = u[i]*Kx[3][i]*vj3;
    *(float4*)(op + i*16) = w;
  }

  // payments_i = frac_i * sum_j allocs_ij * bids_ij   (bids re-read, L1/L3-hot)
  const float* bp = X + e*256 + 4*c;
  float pay[16];
#pragma unroll
  for (int i=0;i<16;++i){
    float4 bb = *(const float4*)(bp + i*16);
    float s = u[i]*(Kx[0][i]*vj0*bb.x + Kx[1][i]*vj1*bb.y + Kx[2][i]*vj2*bb.z + Kx[3][i]*vj3*bb.w);
    pay[i] = qadd2(s);
  }
  float4 pv;
  if      (c==0) pv = make_float4(pay[0],pay[1],pay[2],pay[3]);
  else if (c==1) pv = make_float4(pay[4],pay[5],pay[6],pay[7]);
  else if (c==2) pv = make_float4(pay[8],pay[9],pay[10],pay[11]);
  else           pv = make_float4(pay[12],pay[13],pay[14],pay[15]);
  const float4 fr = *(const float4*)(frac_l + eL*16 + 4*c);
  pv.x *= fr.x; pv.y *= fr.y; pv.z *= fr.z; pv.w *= fr.w;
  *(float4*)(out + (size_t)NB*256 + e*16 + 4*c) = pv;
}

// ================= launch =================
extern "C" void kernel_launch(void* const* d_in, const int* in_sizes, int n_in,
                              void* d_out, int out_size, void* d_ws, size_t ws_size,
                              hipStream_t stream)
{
  const float* bids = (const float*)d_in[0];
  const float* aw0 = (const float*)d_in[1];  const float* ab0 = (const float*)d_in[2];
  const float* aw1 = (const float*)d_in[3];  const float* ab1 = (const float*)d_in[4];
  const float* aw2 = (const float*)d_in[5];  const float* ab2 = (const float*)d_in[6];
  const float* aw3 = (const float*)d_in[7];  const float* ab3 = (const float*)d_in[8];
  const float* pw0 = (const float*)d_in[9];  const float* pb0 = (const float*)d_in[10];
  const float* pw1 = (const float*)d_in[11]; const float* pb1 = (const float*)d_in[12];
  const float* pw2 = (const float*)d_in[13]; const float* pb2 = (const float*)d_in[14];
  const float* pw3 = (const float*)d_in[15]; const float* pb3 = (const float*)d_in[16];

  _Float16* WT = (_Float16*)d_ws;

  PrepJobs js;
  js.j[0] = { aw0, WT+O_AW0H, nullptr,    8, 32768 };
  js.j[1] = { aw1, WT+O_AW1H, WT+O_AW1L,  7, 16384 };
  js.j[2] = { aw2, WT+O_AW2H, WT+O_AW2L,  7, 16384 };
  js.j[3] = { aw3, WT+O_AW3H, WT+O_AW3L,  7, 32768 };
  js.j[4] = { pw0, WT+O_PW0H, nullptr,    8, 32768 };
  js.j[5] = { pw1, WT+O_PW1H, nullptr,    7, 16384 };
  js.j[6] = { pw2, WT+O_PW2H, nullptr,    7, 16384 };
  js.j[7] = { pw3, WT+O_PW3H, nullptr,    7, 2048  };

  prep_kernel<<<dim3(128,8), 256, 0, stream>>>(js);
  fused_kernel<<<dim3(NB/16), 64, 0, stream>>>(bids, WT, ab0,ab1,ab2,ab3,
                                               pb0,pb1,pb2,pb3, (float*)d_out);
}